// Round 5
// baseline (645.114 us; speedup 1.0000x reference)
//
#include <hip/hip_runtime.h>

#define SEQ 768
#define PRED 192
#define ENC 321
#define NB 2
#define BE (NB*ENC)
#define CH 96

typedef float vf2 __attribute__((ext_vector_type(2)));

__device__ __forceinline__ float4 ldg4(const float* p) {
    return *reinterpret_cast<const float4*>(p);
}
__device__ __forceinline__ vf2 fma2(vf2 a, vf2 b, vf2 c) {
    return __builtin_elementwise_fma(a, b, c);
}

__host__ __device__ __forceinline__ int d_Lw(int s)    { return s==0?192:(s==1?384:768); }
__host__ __device__ __forceinline__ int d_Hoff(int s)  { return s==0?0:(s==1?49152:147456); }
__host__ __device__ __forceinline__ int d_twoff(int s) { return s==0?0:(s==1?6144:18432); }

// ------------------------------------------------------------------
__global__ void k_stats(const float* __restrict__ hist,
                        float* __restrict__ meanb, float* __restrict__ stdb) {
    int j  = blockIdx.x*64 + threadIdx.x;
    int b  = blockIdx.y;
    int ty = threadIdx.y;
    float s = 0.f, s2 = 0.f;
    if (j < ENC) {
        for (int t = ty; t < SEQ; t += 4) {
            float v = hist[(size_t)b*SEQ*ENC + (size_t)t*ENC + j];
            s += v; s2 += v*v;
        }
    }
    __shared__ float l1[4][64], l2[4][64];
    l1[ty][threadIdx.x] = s; l2[ty][threadIdx.x] = s2;
    __syncthreads();
    if (ty == 0 && j < ENC) {
        float S  = l1[0][threadIdx.x]+l1[1][threadIdx.x]+l1[2][threadIdx.x]+l1[3][threadIdx.x];
        float S2 = l2[0][threadIdx.x]+l2[1][threadIdx.x]+l2[2][threadIdx.x]+l2[3][threadIdx.x];
        float m   = S * (1.f/SEQ);
        float var = S2 * (1.f/SEQ) - m*m;
        meanb[b*ENC+j] = m;
        stdb[b*ENC+j]  = sqrtf(var + 1e-5f);
    }
}

__global__ void k_norm(const float* __restrict__ hist,
                       const float* __restrict__ meanb, const float* __restrict__ stdb,
                       const float* __restrict__ aw, const float* __restrict__ ab,
                       float* __restrict__ xn) {
    int i = blockIdx.x*256 + threadIdx.x;
    if (i >= NB*SEQ*ENC) return;
    int j = i % ENC;
    int b = i / (SEQ*ENC);
    float v = (hist[i] - meanb[b*ENC+j]) / stdb[b*ENC+j];
    xn[i] = v * aw[j] + ab[j];
}

// twm[s][m][k] = e^{-2pi i k m / Lw};  gtm[s][r][k] = kappa_k e^{+2pi i k (191-r)/Lw}
__global__ void k_tw(float2* __restrict__ twm, float2* __restrict__ gtm) {
    int i = blockIdx.x*256 + threadIdx.x;
    if (i >= 43008) return;
    int s, rem;
    if (i < 6144)       { s=0; rem=i; }
    else if (i < 18432) { s=1; rem=i-6144; }
    else                { s=2; rem=i-18432; }
    int Lw = d_Lw(s);
    int k = rem & 31, m = rem >> 5;
    const float TWO_PI = 6.28318530717958647692f;
    int km = (k*m) % Lw;
    float c, sn;
    sincosf(TWO_PI * km / Lw, &sn, &c);
    twm[i] = make_float2(c, -sn);
    int e = (k*(PRED-1-m)) % Lw; if (e < 0) e += Lw;
    float c2, s2v;
    sincosf(TWO_PI * e / Lw, &s2v, &c2);
    float coef = (k==0 ? 1.f : 2.f) / (float)Lw;
    gtm[i] = make_float2(coef*c2, coef*s2v);
}

__global__ void k_hinit(const float* __restrict__ Ast, const float* __restrict__ Bst,
                        float* __restrict__ apow, float* __restrict__ Hbuf) {
    int i = blockIdx.x*256 + threadIdx.x;
    if (i < 3*65536) apow[i] = Ast[i];
    if (i < 3*256) {
        int s = i >> 8, n = i & 255;
        Hbuf[d_Hoff(s) + n] = Bst[i];
    }
}

// ---------- 64x64 tile GEMM cores (pk-fma + register prefetch) ----------
// NT: C[m,n] = sum_q A[m,q]*B[n,q]
__device__ __forceinline__ void gemm64nt(
    const float* __restrict__ A, int lda, int Arows,
    const float* __restrict__ B, int ldb,
    float* __restrict__ C, int ldc, int m0, int n0, int K)
{
    __shared__ __align__(16) float AsT[16][68];
    __shared__ __align__(16) float BsT[16][68];
    int tid = threadIdx.x;
    int tm = tid >> 4, tn = tid & 15;
    int lr = tid >> 2, lq = (tid & 3)*4;
    bool aok = (m0 + lr) < Arows;
    const float* Ap = A + (size_t)(m0+lr)*lda + lq;
    const float* Bp = B + (size_t)(n0+lr)*ldb + lq;
    float4 fa = aok ? ldg4(Ap) : make_float4(0.f,0.f,0.f,0.f);
    float4 fb = ldg4(Bp);
    vf2 acc[2][4] = {};
    for (int kt = 0; kt < K; kt += 16) {
        __syncthreads();
        AsT[lq+0][lr]=fa.x; AsT[lq+1][lr]=fa.y; AsT[lq+2][lr]=fa.z; AsT[lq+3][lr]=fa.w;
        BsT[lq+0][lr]=fb.x; BsT[lq+1][lr]=fb.y; BsT[lq+2][lr]=fb.z; BsT[lq+3][lr]=fb.w;
        __syncthreads();
        if (kt + 16 < K) {
            fa = aok ? ldg4(Ap + kt + 16) : make_float4(0.f,0.f,0.f,0.f);
            fb = ldg4(Bp + kt + 16);
        }
        #pragma unroll
        for (int q = 0; q < 16; q++) {
            float4 a = *reinterpret_cast<float4*>(&AsT[q][tm*4]);
            float4 b = *reinterpret_cast<float4*>(&BsT[q][tn*4]);
            vf2 a01 = {a.x, a.y}, a23 = {a.z, a.w};
            vf2 b0 = {b.x,b.x}, b1 = {b.y,b.y}, b2 = {b.z,b.z}, b3 = {b.w,b.w};
            acc[0][0] = fma2(a01, b0, acc[0][0]);
            acc[0][1] = fma2(a01, b1, acc[0][1]);
            acc[0][2] = fma2(a01, b2, acc[0][2]);
            acc[0][3] = fma2(a01, b3, acc[0][3]);
            acc[1][0] = fma2(a23, b0, acc[1][0]);
            acc[1][1] = fma2(a23, b1, acc[1][1]);
            acc[1][2] = fma2(a23, b2, acc[1][2]);
            acc[1][3] = fma2(a23, b3, acc[1][3]);
        }
    }
    #pragma unroll
    for (int h = 0; h < 2; h++) {
        int m = m0 + tm*4 + h*2;
        #pragma unroll
        for (int j = 0; j < 4; j++) {
            if (m < Arows)     C[(size_t)m*ldc + n0 + tn*4 + j]     = acc[h][j].x;
            if (m + 1 < Arows) C[(size_t)(m+1)*ldc + n0 + tn*4 + j] = acc[h][j].y;
        }
    }
}

// NN: C[m,n] = sum_q A[m,q]*B[q,n]
__device__ __forceinline__ void gemm64nn(
    const float* __restrict__ A, int lda,
    const float* __restrict__ B, int ldb,
    float* __restrict__ C, int ldc, int m0, int n0, int K)
{
    __shared__ __align__(16) float AsT[16][68];
    __shared__ __align__(16) float Bs[16][68];
    int tid = threadIdx.x;
    int tm = tid >> 4, tn = tid & 15;
    int lr = tid >> 2, lq = (tid & 3)*4;
    int blq = tid >> 4, blc = (tid & 15)*4;
    const float* Ap = A + (size_t)(m0+lr)*lda + lq;
    const float* Bp = B + (size_t)blq*ldb + n0 + blc;
    float4 fa = ldg4(Ap);
    float4 fb = ldg4(Bp);
    vf2 acc[2][4] = {};
    for (int kt = 0; kt < K; kt += 16) {
        __syncthreads();
        AsT[lq+0][lr]=fa.x; AsT[lq+1][lr]=fa.y; AsT[lq+2][lr]=fa.z; AsT[lq+3][lr]=fa.w;
        *reinterpret_cast<float4*>(&Bs[blq][blc]) = fb;
        __syncthreads();
        if (kt + 16 < K) {
            fa = ldg4(Ap + kt + 16);
            fb = ldg4(Bp + (size_t)(kt+16)*ldb);
        }
        #pragma unroll
        for (int q = 0; q < 16; q++) {
            float4 a = *reinterpret_cast<float4*>(&AsT[q][tm*4]);
            float4 b = *reinterpret_cast<float4*>(&Bs[q][tn*4]);
            vf2 a01 = {a.x, a.y}, a23 = {a.z, a.w};
            vf2 b0 = {b.x,b.x}, b1 = {b.y,b.y}, b2 = {b.z,b.z}, b3 = {b.w,b.w};
            acc[0][0] = fma2(a01, b0, acc[0][0]);
            acc[0][1] = fma2(a01, b1, acc[0][1]);
            acc[0][2] = fma2(a01, b2, acc[0][2]);
            acc[0][3] = fma2(a01, b3, acc[0][3]);
            acc[1][0] = fma2(a23, b0, acc[1][0]);
            acc[1][1] = fma2(a23, b1, acc[1][1]);
            acc[1][2] = fma2(a23, b2, acc[1][2]);
            acc[1][3] = fma2(a23, b3, acc[1][3]);
        }
    }
    #pragma unroll
    for (int h = 0; h < 2; h++) {
        int m = m0 + tm*4 + h*2;
        #pragma unroll
        for (int j = 0; j < 4; j++) {
            C[(size_t)m*ldc + n0 + tn*4 + j]     = acc[h][j].x;
            C[(size_t)(m+1)*ldc + n0 + tn*4 + j] = acc[h][j].y;
        }
    }
}

// one doubling level: fill H[mc..min(2mc,Lw)) = H[0..]*Apow^T ; square Apow
__global__ void __launch_bounds__(256) k_hlevel(float* __restrict__ Hbuf,
                                                float* __restrict__ apow,
                                                int par, int mc) {
    int s = blockIdx.z;
    int Lw = d_Lw(s);
    const float* Asrc = apow + (size_t)par*196608 + (size_t)s*65536;
    float* Adst       = apow + (size_t)(1-par)*196608 + (size_t)s*65536;
    float* H = Hbuf + d_Hoff(s);
    int yt = blockIdx.y, xt = blockIdx.x;
    if (yt < 4) {
        if (mc >= Lw) return;
        int rows = min(mc, Lw - mc);
        if (yt*64 >= rows) return;
        gemm64nt(H, 256, rows, Asrc, 256, H + (size_t)mc*256, 256,
                 yt*64, xt*64, 256);
    } else {
        if (2*mc >= Lw) return;
        gemm64nn(Asrc, 256, Asrc, 256, Adst, 256, (yt-4)*64, xt*64, 256);
    }
}

// transpose H (Lw x 256) -> HT (256 x Lw), per scale
__global__ void k_htr(const float* __restrict__ Hbuf, float* __restrict__ HT) {
    int i = blockIdx.x*256 + threadIdx.x;
    if (i >= 344064) return;
    int s, rem;
    if (i < 49152)       { s=0; rem=i; }
    else if (i < 147456) { s=1; rem=i-49152; }
    else                 { s=2; rem=i-147456; }
    int Lw = d_Lw(s);
    int k = rem / Lw, m = rem - k*Lw;
    HT[i] = Hbuf[d_Hoff(s) + (size_t)m*256 + k];
}

// Bpack[n][o*64 + k*2 + c] = (c ? wi : wr)[s][n,o,k]
__global__ void k_pack2(const float* __restrict__ wr, const float* __restrict__ wi,
                        float* __restrict__ Bp, int s) {
    int idx = blockIdx.x*256 + threadIdx.x;
    int n = idx >> 14, j = idx & 16383;
    int o = j >> 6, kc = j & 63, k = kc >> 1, c = kc & 1;
    const float* W = (c ? wi : wr) + (size_t)s*2097152;
    Bp[idx] = W[(size_t)n*8192 + o*32 + k];
}

// Call (Lw x 16384) = HT^T (Lw x 256) * Bpack (256 x 16384)
// 128x128 tiles, 8x8 per-thread acc, K=256
__global__ void __launch_bounds__(256) k_cgemm(
    const float* __restrict__ HT, const float* __restrict__ Bp,
    float* __restrict__ C, int Lw)
{
    int m0 = blockIdx.x*128, n0 = blockIdx.y*128;
    __shared__ __align__(16) float As[16][132];
    __shared__ __align__(16) float Bs[16][132];
    int tid = threadIdx.x;
    int ty = tid >> 4, tx = tid & 15;
    int lq = tid >> 5;           // 0..7
    int lc = (tid & 31) * 4;     // 0..124
    const float* Ap0 = HT + (size_t)lq*Lw + m0 + lc;
    const float* Ap1 = HT + (size_t)(lq+8)*Lw + m0 + lc;
    const float* Bq0 = Bp + (size_t)lq*16384 + n0 + lc;
    const float* Bq1 = Bp + (size_t)(lq+8)*16384 + n0 + lc;
    float4 fa0 = ldg4(Ap0), fa1 = ldg4(Ap1);
    float4 fb0 = ldg4(Bq0), fb1 = ldg4(Bq1);
    vf2 acc[4][8] = {};
    for (int kt = 0; kt < 256; kt += 16) {
        __syncthreads();
        *reinterpret_cast<float4*>(&As[lq][lc])   = fa0;
        *reinterpret_cast<float4*>(&As[lq+8][lc]) = fa1;
        *reinterpret_cast<float4*>(&Bs[lq][lc])   = fb0;
        *reinterpret_cast<float4*>(&Bs[lq+8][lc]) = fb1;
        __syncthreads();
        if (kt + 16 < 256) {
            fa0 = ldg4(Ap0 + (size_t)(kt+16)*Lw);
            fa1 = ldg4(Ap1 + (size_t)(kt+16)*Lw);
            fb0 = ldg4(Bq0 + (size_t)(kt+16)*16384);
            fb1 = ldg4(Bq1 + (size_t)(kt+16)*16384);
        }
        #pragma unroll
        for (int q = 0; q < 16; q++) {
            float4 a0 = *reinterpret_cast<float4*>(&As[q][ty*8]);
            float4 a1 = *reinterpret_cast<float4*>(&As[q][ty*8+4]);
            float4 b0 = *reinterpret_cast<float4*>(&Bs[q][tx*4]);
            float4 b1 = *reinterpret_cast<float4*>(&Bs[q][64+tx*4]);
            vf2 ap[4] = {{a0.x,a0.y},{a0.z,a0.w},{a1.x,a1.y},{a1.z,a1.w}};
            float bv[8] = {b0.x,b0.y,b0.z,b0.w,b1.x,b1.y,b1.z,b1.w};
            #pragma unroll
            for (int rp = 0; rp < 4; rp++) {
                #pragma unroll
                for (int j = 0; j < 8; j++) {
                    vf2 bb = {bv[j], bv[j]};
                    acc[rp][j] = fma2(ap[rp], bb, acc[rp][j]);
                }
            }
        }
    }
    #pragma unroll
    for (int rp = 0; rp < 4; rp++) {
        int r0 = m0 + ty*8 + rp*2;
        if (r0 < Lw) {
            float* p = C + (size_t)r0*16384 + n0 + tx*4;
            *reinterpret_cast<float4*>(p)    = make_float4(acc[rp][0].x, acc[rp][1].x, acc[rp][2].x, acc[rp][3].x);
            *reinterpret_cast<float4*>(p+64) = make_float4(acc[rp][4].x, acc[rp][5].x, acc[rp][6].x, acc[rp][7].x);
        }
        if (r0 + 1 < Lw) {
            float* p = C + (size_t)(r0+1)*16384 + n0 + tx*4;
            *reinterpret_cast<float4*>(p)    = make_float4(acc[rp][0].y, acc[rp][1].y, acc[rp][2].y, acc[rp][3].y);
            *reinterpret_cast<float4*>(p+64) = make_float4(acc[rp][4].y, acc[rp][5].y, acc[rp][6].y, acc[rp][7].y);
        }
    }
}

// pass 1 of m-scan over Call: per-chunk complex partials of sum_m w^m * Ck[m,o]
__global__ void k_cscan1(const float2* __restrict__ Call2, const float2* __restrict__ twm,
                         float2* __restrict__ psum, int s, int cgbase) {
    int cl = blockIdx.x;
    int tid = threadIdx.x;
    int k = tid & 31, ol = tid >> 5;
    int o = blockIdx.y*8 + ol;
    const float2* tws = twm + d_twoff(s);
    int mbase = cl*CH;
    float pr = 0.f, pi = 0.f;
    for (int mm = 0; mm < CH; mm++) {
        int m = mbase + mm;
        float2 cc = Call2[(size_t)m*8192 + o*32 + k];
        float2 t  = tws[(size_t)m*32 + k];
        pr = fmaf(t.x, cc.x, pr); pr = fmaf(-t.y, cc.y, pr);
        pi = fmaf(t.x, cc.y, pi); pi = fmaf(t.y, cc.x, pi);
    }
    psum[((size_t)(cgbase+cl))*8192 + o*32 + k] = make_float2(pr, pi);
}

// pass 2: rescan with chunk offset, contract over k -> Qall rows
__global__ void k_cscan2(const float2* __restrict__ Call2, const float2* __restrict__ twm,
                         const float2* __restrict__ gtm, const float2* __restrict__ psum,
                         float* __restrict__ Qrow, int s, int cgbase, int Lw) {
    int cl = blockIdx.x;
    int tid = threadIdx.x;
    int k = tid & 31, ol = tid >> 5;
    int o = blockIdx.y*8 + ol;
    const float2* tws = twm + d_twoff(s);
    const float2* gts = gtm + d_twoff(s);
    float pr = 0.f, pi = 0.f;
    for (int c = 0; c < cl; c++) {
        float2 p = psum[((size_t)(cgbase+c))*8192 + o*32 + k];
        pr += p.x; pi += p.y;
    }
    int mbase = cl*CH;
    for (int mm = 0; mm < CH; mm++) {
        int m = mbase + mm;
        float2 cc = Call2[(size_t)m*8192 + o*32 + k];
        float2 t  = tws[(size_t)m*32 + k];
        pr = fmaf(t.x, cc.x, pr); pr = fmaf(-t.y, cc.y, pr);
        pi = fmaf(t.x, cc.y, pi); pi = fmaf(t.y, cc.x, pi);
        int r = Lw - 1 - m;
        float2 g = gts[(size_t)r*32 + k];
        float qv = g.x*pr - g.y*pi;
        qv += __shfl_xor(qv, 16);
        qv += __shfl_xor(qv, 8);
        qv += __shfl_xor(qv, 4);
        qv += __shfl_xor(qv, 2);
        qv += __shfl_xor(qv, 1);
        if (k == 0) Qrow[(size_t)r*256 + o] = qv;
    }
}

// T[r,p] = sum_o Q[r,o] * Esub[p,o]   (batched over all scales)
__global__ void __launch_bounds__(256) k_tgemm(const float* __restrict__ Qall,
                                               const float* __restrict__ E0,
                                               const float* __restrict__ E1,
                                               const float* __restrict__ E2,
                                               float* __restrict__ T) {
    int mtg = blockIdx.x;
    int s, lm, Lw, rowoff, Toff;
    if (mtg < 3)      { s=0; lm=mtg;   Lw=192; rowoff=0;   Toff=0; }
    else if (mtg < 9) { s=1; lm=mtg-3; Lw=384; rowoff=192; Toff=36864; }
    else              { s=2; lm=mtg-9; Lw=768; rowoff=576; Toff=110592; }
    const float* Es = (s==0) ? E0 : ((s==1) ? E1 : E2);
    gemm64nt(Qall + (size_t)rowoff*256, 256, Lw,
             Es + (size_t)(Lw-192)*256, 256,
             T + Toff, 192, lm*64, blockIdx.y*64, 256);
}

// Mtot[p,t] = sum_i mw[i] * T_i[t-off_i, p]
__global__ void k_mtot(const float* __restrict__ T, const float* __restrict__ mlpw,
                       float* __restrict__ M) {
    int i = blockIdx.x*256 + threadIdx.x;
    if (i >= 192*768) return;
    int p = i / 768, t = i % 768;
    float v = mlpw[2] * T[110592 + (size_t)t*192 + p];
    if (t >= 384) v += mlpw[1] * T[36864 + (size_t)(t-384)*192 + p];
    if (t >= 576) v += mlpw[0] * T[(size_t)(t-576)*192 + p];
    M[i] = v;
}

// out[b,p,j] = ((Mtot @ x)[p,(b,j)] + mb - ab[j])/(aw[j]+1e-10)*std + mean
__global__ void __launch_bounds__(256) k_final(
    const float* __restrict__ M, const float* __restrict__ xn,
    const float* __restrict__ aw, const float* __restrict__ ab,
    const float* __restrict__ meanb, const float* __restrict__ stdb,
    const float* __restrict__ mlpb, float* __restrict__ out)
{
    __shared__ float Ls[64][17];
    __shared__ float Bs[16][65];
    int p0 = blockIdx.x*64, c0 = blockIdx.y*64;
    int tid = threadIdx.x, tm = tid >> 4, tn = tid & 15;
    float acc[4][4] = {};
    for (int kt = 0; kt < 768; kt += 16) {
        __syncthreads();
        #pragma unroll
        for (int e = 0; e < 4; e++) {
            int idx = tid + e*256;
            int r = idx >> 4, q = idx & 15;
            Ls[r][q] = M[(size_t)(p0+r)*768 + kt + q];
        }
        #pragma unroll
        for (int e = 0; e < 4; e++) {
            int idx = tid + e*256;
            int q = idx >> 6, c = idx & 63;
            int cc = c0 + c;
            float v = 0.f;
            if (cc < BE) {
                int b = (cc >= ENC) ? 1 : 0;
                int j = cc - b*ENC;
                v = xn[(size_t)b*SEQ*ENC + (size_t)(kt+q)*ENC + j];
            }
            Bs[q][c] = v;
        }
        __syncthreads();
        #pragma unroll
        for (int q = 0; q < 16; q++) {
            float a[4], bb[4];
            #pragma unroll
            for (int i = 0; i < 4; i++) a[i]  = Ls[tm*4+i][q];
            #pragma unroll
            for (int j = 0; j < 4; j++) bb[j] = Bs[q][tn*4+j];
            #pragma unroll
            for (int i = 0; i < 4; i++)
                #pragma unroll
                for (int j = 0; j < 4; j++)
                    acc[i][j] = fmaf(a[i], bb[j], acc[i][j]);
        }
    }
    float mb = mlpb[0];
    #pragma unroll
    for (int i = 0; i < 4; i++) {
        int p = p0 + tm*4 + i;
        #pragma unroll
        for (int j = 0; j < 4; j++) {
            int cc = c0 + tn*4 + j;
            if (cc < BE) {
                int b = (cc >= ENC) ? 1 : 0;
                int jj = cc - b*ENC;
                float v = (acc[i][j] + mb - ab[jj]) / (aw[jj] + 1e-10f);
                v = v * stdb[b*ENC+jj] + meanb[b*ENC+jj];
                out[(size_t)b*(PRED*ENC) + (size_t)p*ENC + jj] = v;
            }
        }
    }
}

// ------------------------------------------------------------------
extern "C" void kernel_launch(void* const* d_in, const int* in_sizes, int n_in,
                              void* d_out, int out_size, void* d_ws, size_t ws_size,
                              hipStream_t stream)
{
    const float* hist = (const float*)d_in[0];
    const float* aw   = (const float*)d_in[2];
    const float* ab   = (const float*)d_in[3];
    const float* Ast  = (const float*)d_in[4];
    const float* Bst  = (const float*)d_in[5];
    const float* E0   = (const float*)d_in[6];
    const float* E1   = (const float*)d_in[7];
    const float* E2   = (const float*)d_in[8];
    const float* wr   = (const float*)d_in[9];
    const float* wi   = (const float*)d_in[10];
    const float* mlpw = (const float*)d_in[11];
    const float* mlpb = (const float*)d_in[12];
    float* out = (float*)d_out;

    float* w = (float*)d_ws;
    float* xn    = w; w += 493056;
    float* meanb = w; w += 642;
    float* stdb  = w; w += 642;
    float* Hbuf  = w; w += 344064;
    float* HT    = w; w += 344064;
    float* apow  = w; w += 393216;
    float2* twm  = (float2*)w; w += 86016;
    float2* gtm  = (float2*)w; w += 86016;
    float2* psum = (float2*)w; w += 229376;
    float* Bpack = w; w += 4194304;           // 256 x 16384 (per scale, reused)
    float* Call  = w; w += 12582912;          // up to 768 x 16384 (per scale, reused)
    float* Qall  = w; w += 344064;            // 1344 x 256
    float* Tbuf  = w; w += 258048;
    float* Mt    = w; w += 147456;
    // total ~19.5M floats = 78.0 MB (< 89.2 MB proven)

    k_stats<<<dim3(6,2), dim3(64,4), 0, stream>>>(hist, meanb, stdb);
    k_norm<<<1926, 256, 0, stream>>>(hist, meanb, stdb, aw, ab, xn);
    k_tw<<<168, 256, 0, stream>>>(twm, gtm);
    k_hinit<<<768, 256, 0, stream>>>(Ast, Bst, apow, Hbuf);
    for (int lev = 0; lev < 10; lev++)
        k_hlevel<<<dim3(4,8,3), 256, 0, stream>>>(Hbuf, apow, lev & 1, 1 << lev);
    k_htr<<<1344, 256, 0, stream>>>(Hbuf, HT);

    const int Lws[3]    = {192, 384, 768};
    const int cgbase[3] = {0, 2, 6};
    const int rowoff[3] = {0, 192, 576};
    for (int s = 0; s < 3; s++) {
        int Lw = Lws[s];
        int nch = Lw / CH;
        int mt  = (Lw + 127) / 128;
        k_pack2<<<16384, 256, 0, stream>>>(wr, wi, Bpack, s);
        k_cgemm<<<dim3(mt, 128), 256, 0, stream>>>(HT + d_Hoff(s), Bpack, Call, Lw);
        k_cscan1<<<dim3(nch, 32), 256, 0, stream>>>((const float2*)Call, twm, psum, s, cgbase[s]);
        k_cscan2<<<dim3(nch, 32), 256, 0, stream>>>((const float2*)Call, twm, gtm, psum,
                                                    Qall + (size_t)rowoff[s]*256, s, cgbase[s], Lw);
    }
    k_tgemm<<<dim3(21,3), 256, 0, stream>>>(Qall, E0, E1, E2, Tbuf);
    k_mtot<<<576, 256, 0, stream>>>(Tbuf, mlpw, Mt);
    k_final<<<dim3(3, 11), 256, 0, stream>>>(Mt, xn, ab ? aw : aw, ab, meanb, stdb, mlpb, out);
}

// Round 6
// 532.906 us; speedup vs baseline: 1.2106x; 1.2106x over previous
//
#include <hip/hip_runtime.h>

#define SEQ 768
#define PRED 192
#define ENC 321
#define NB 2
#define BE (NB*ENC)
#define CH 48

typedef float vf2 __attribute__((ext_vector_type(2)));

__device__ __forceinline__ float4 ldg4(const float* p) {
    return *reinterpret_cast<const float4*>(p);
}
__device__ __forceinline__ float2 ldg2(const float* p) {
    return *reinterpret_cast<const float2*>(p);
}
__device__ __forceinline__ vf2 fma2(vf2 a, vf2 b, vf2 c) {
    return __builtin_elementwise_fma(a, b, c);
}

__host__ __device__ __forceinline__ int d_Lw(int s)    { return s==0?192:(s==1?384:768); }
__host__ __device__ __forceinline__ int d_Hoff(int s)  { return s==0?0:(s==1?49152:147456); }
__host__ __device__ __forceinline__ int d_twoff(int s) { return s==0?0:(s==1?6144:18432); }

// ------------------------------------------------------------------
__global__ void k_stats(const float* __restrict__ hist,
                        float* __restrict__ meanb, float* __restrict__ stdb) {
    int j  = blockIdx.x*64 + threadIdx.x;
    int b  = blockIdx.y;
    int ty = threadIdx.y;
    float s = 0.f, s2 = 0.f;
    if (j < ENC) {
        for (int t = ty; t < SEQ; t += 4) {
            float v = hist[(size_t)b*SEQ*ENC + (size_t)t*ENC + j];
            s += v; s2 += v*v;
        }
    }
    __shared__ float l1[4][64], l2[4][64];
    l1[ty][threadIdx.x] = s; l2[ty][threadIdx.x] = s2;
    __syncthreads();
    if (ty == 0 && j < ENC) {
        float S  = l1[0][threadIdx.x]+l1[1][threadIdx.x]+l1[2][threadIdx.x]+l1[3][threadIdx.x];
        float S2 = l2[0][threadIdx.x]+l2[1][threadIdx.x]+l2[2][threadIdx.x]+l2[3][threadIdx.x];
        float m   = S * (1.f/SEQ);
        float var = S2 * (1.f/SEQ) - m*m;
        meanb[b*ENC+j] = m;
        stdb[b*ENC+j]  = sqrtf(var + 1e-5f);
    }
}

__global__ void k_norm(const float* __restrict__ hist,
                       const float* __restrict__ meanb, const float* __restrict__ stdb,
                       const float* __restrict__ aw, const float* __restrict__ ab,
                       float* __restrict__ xn) {
    int i = blockIdx.x*256 + threadIdx.x;
    if (i >= NB*SEQ*ENC) return;
    int j = i % ENC;
    int b = i / (SEQ*ENC);
    float v = (hist[i] - meanb[b*ENC+j]) / stdb[b*ENC+j];
    xn[i] = v * aw[j] + ab[j];
}

// twm[s][m][k] = e^{-2pi i k m / Lw};  gtm[s][r][k] = kappa_k e^{+2pi i k (191-r)/Lw}
__global__ void k_tw(float2* __restrict__ twm, float2* __restrict__ gtm) {
    int i = blockIdx.x*256 + threadIdx.x;
    if (i >= 43008) return;
    int s, rem;
    if (i < 6144)       { s=0; rem=i; }
    else if (i < 18432) { s=1; rem=i-6144; }
    else                { s=2; rem=i-18432; }
    int Lw = d_Lw(s);
    int k = rem & 31, m = rem >> 5;
    const float TWO_PI = 6.28318530717958647692f;
    int km = (k*m) % Lw;
    float c, sn;
    sincosf(TWO_PI * km / Lw, &sn, &c);
    twm[i] = make_float2(c, -sn);
    int e = (k*(PRED-1-m)) % Lw; if (e < 0) e += Lw;
    float c2, s2v;
    sincosf(TWO_PI * e / Lw, &s2v, &c2);
    float coef = (k==0 ? 1.f : 2.f) / (float)Lw;
    gtm[i] = make_float2(coef*c2, coef*s2v);
}

__global__ void k_hinit(const float* __restrict__ Ast, const float* __restrict__ Bst,
                        float* __restrict__ apow, float* __restrict__ Hbuf) {
    int i = blockIdx.x*256 + threadIdx.x;
    if (i < 3*65536) apow[i] = Ast[i];
    if (i < 3*256) {
        int s = i >> 8, n = i & 255;
        Hbuf[d_Hoff(s) + n] = Bst[i];
    }
}

// ---------- 64x64 tile GEMM cores (pk-fma + register prefetch) ----------
// NT: C[m,n] = sum_q A[m,q]*B[n,q]
__device__ __forceinline__ void gemm64nt(
    const float* __restrict__ A, int lda, int Arows,
    const float* __restrict__ B, int ldb,
    float* __restrict__ C, int ldc, int m0, int n0, int K)
{
    __shared__ __align__(16) float AsT[16][68];
    __shared__ __align__(16) float BsT[16][68];
    int tid = threadIdx.x;
    int tm = tid >> 4, tn = tid & 15;
    int lr = tid >> 2, lq = (tid & 3)*4;
    bool aok = (m0 + lr) < Arows;
    const float* Ap = A + (size_t)(m0+lr)*lda + lq;
    const float* Bp = B + (size_t)(n0+lr)*ldb + lq;
    float4 fa = aok ? ldg4(Ap) : make_float4(0.f,0.f,0.f,0.f);
    float4 fb = ldg4(Bp);
    vf2 acc[2][4] = {};
    for (int kt = 0; kt < K; kt += 16) {
        __syncthreads();
        AsT[lq+0][lr]=fa.x; AsT[lq+1][lr]=fa.y; AsT[lq+2][lr]=fa.z; AsT[lq+3][lr]=fa.w;
        BsT[lq+0][lr]=fb.x; BsT[lq+1][lr]=fb.y; BsT[lq+2][lr]=fb.z; BsT[lq+3][lr]=fb.w;
        __syncthreads();
        if (kt + 16 < K) {
            fa = aok ? ldg4(Ap + kt + 16) : make_float4(0.f,0.f,0.f,0.f);
            fb = ldg4(Bp + kt + 16);
        }
        #pragma unroll
        for (int q = 0; q < 16; q++) {
            float4 a = *reinterpret_cast<float4*>(&AsT[q][tm*4]);
            float4 b = *reinterpret_cast<float4*>(&BsT[q][tn*4]);
            vf2 a01 = {a.x, a.y}, a23 = {a.z, a.w};
            vf2 b0 = {b.x,b.x}, b1 = {b.y,b.y}, b2 = {b.z,b.z}, b3 = {b.w,b.w};
            acc[0][0] = fma2(a01, b0, acc[0][0]);
            acc[0][1] = fma2(a01, b1, acc[0][1]);
            acc[0][2] = fma2(a01, b2, acc[0][2]);
            acc[0][3] = fma2(a01, b3, acc[0][3]);
            acc[1][0] = fma2(a23, b0, acc[1][0]);
            acc[1][1] = fma2(a23, b1, acc[1][1]);
            acc[1][2] = fma2(a23, b2, acc[1][2]);
            acc[1][3] = fma2(a23, b3, acc[1][3]);
        }
    }
    #pragma unroll
    for (int h = 0; h < 2; h++) {
        int m = m0 + tm*4 + h*2;
        #pragma unroll
        for (int j = 0; j < 4; j++) {
            if (m < Arows)     C[(size_t)m*ldc + n0 + tn*4 + j]     = acc[h][j].x;
            if (m + 1 < Arows) C[(size_t)(m+1)*ldc + n0 + tn*4 + j] = acc[h][j].y;
        }
    }
}

// NN: C[m,n] = sum_q A[m,q]*B[q,n]
__device__ __forceinline__ void gemm64nn(
    const float* __restrict__ A, int lda,
    const float* __restrict__ B, int ldb,
    float* __restrict__ C, int ldc, int m0, int n0, int K)
{
    __shared__ __align__(16) float AsT[16][68];
    __shared__ __align__(16) float Bs[16][68];
    int tid = threadIdx.x;
    int tm = tid >> 4, tn = tid & 15;
    int lr = tid >> 2, lq = (tid & 3)*4;
    int blq = tid >> 4, blc = (tid & 15)*4;
    const float* Ap = A + (size_t)(m0+lr)*lda + lq;
    const float* Bp = B + (size_t)blq*ldb + n0 + blc;
    float4 fa = ldg4(Ap);
    float4 fb = ldg4(Bp);
    vf2 acc[2][4] = {};
    for (int kt = 0; kt < K; kt += 16) {
        __syncthreads();
        AsT[lq+0][lr]=fa.x; AsT[lq+1][lr]=fa.y; AsT[lq+2][lr]=fa.z; AsT[lq+3][lr]=fa.w;
        *reinterpret_cast<float4*>(&Bs[blq][blc]) = fb;
        __syncthreads();
        if (kt + 16 < K) {
            fa = ldg4(Ap + kt + 16);
            fb = ldg4(Bp + (size_t)(kt+16)*ldb);
        }
        #pragma unroll
        for (int q = 0; q < 16; q++) {
            float4 a = *reinterpret_cast<float4*>(&AsT[q][tm*4]);
            float4 b = *reinterpret_cast<float4*>(&Bs[q][tn*4]);
            vf2 a01 = {a.x, a.y}, a23 = {a.z, a.w};
            vf2 b0 = {b.x,b.x}, b1 = {b.y,b.y}, b2 = {b.z,b.z}, b3 = {b.w,b.w};
            acc[0][0] = fma2(a01, b0, acc[0][0]);
            acc[0][1] = fma2(a01, b1, acc[0][1]);
            acc[0][2] = fma2(a01, b2, acc[0][2]);
            acc[0][3] = fma2(a01, b3, acc[0][3]);
            acc[1][0] = fma2(a23, b0, acc[1][0]);
            acc[1][1] = fma2(a23, b1, acc[1][1]);
            acc[1][2] = fma2(a23, b2, acc[1][2]);
            acc[1][3] = fma2(a23, b3, acc[1][3]);
        }
    }
    #pragma unroll
    for (int h = 0; h < 2; h++) {
        int m = m0 + tm*4 + h*2;
        #pragma unroll
        for (int j = 0; j < 4; j++) {
            C[(size_t)m*ldc + n0 + tn*4 + j]     = acc[h][j].x;
            C[(size_t)(m+1)*ldc + n0 + tn*4 + j] = acc[h][j].y;
        }
    }
}

// one doubling level: fill H[mc..min(2mc,Lw)) = H[0..]*Apow^T ; square Apow
__global__ void __launch_bounds__(256) k_hlevel(float* __restrict__ Hbuf,
                                                float* __restrict__ apow,
                                                int par, int mc) {
    int s = blockIdx.z;
    int Lw = d_Lw(s);
    const float* Asrc = apow + (size_t)par*196608 + (size_t)s*65536;
    float* Adst       = apow + (size_t)(1-par)*196608 + (size_t)s*65536;
    float* H = Hbuf + d_Hoff(s);
    int yt = blockIdx.y, xt = blockIdx.x;
    if (yt < 4) {
        if (mc >= Lw) return;
        int rows = min(mc, Lw - mc);
        if (yt*64 >= rows) return;
        gemm64nt(H, 256, rows, Asrc, 256, H + (size_t)mc*256, 256,
                 yt*64, xt*64, 256);
    } else {
        if (2*mc >= Lw) return;
        gemm64nn(Asrc, 256, Asrc, 256, Adst, 256, (yt-4)*64, xt*64, 256);
    }
}

// transpose H (Lw x 256) -> HT (256 x Lw), per scale
__global__ void k_htr(const float* __restrict__ Hbuf, float* __restrict__ HT) {
    int i = blockIdx.x*256 + threadIdx.x;
    if (i >= 344064) return;
    int s, rem;
    if (i < 49152)       { s=0; rem=i; }
    else if (i < 147456) { s=1; rem=i-49152; }
    else                 { s=2; rem=i-147456; }
    int Lw = d_Lw(s);
    int k = rem / Lw, m = rem - k*Lw;
    HT[i] = Hbuf[d_Hoff(s) + (size_t)m*256 + k];
}

// Call (Lw x 16384) = HT^T (Lw x 256) * Bpack (256 x 16384)
// Bpack is NOT materialized: col = o*64 + k*2 + c maps to (c?wi:wr)[n,o,k],
// loaded as two float2 + register swizzle.
// 128x128 tiles, 8x8 per-thread acc, K=256.
__global__ void __launch_bounds__(256) k_cgemm(
    const float* __restrict__ HT, const float* __restrict__ wrS,
    const float* __restrict__ wiS, float* __restrict__ C, int Lw)
{
    int m0 = blockIdx.x*128, n0 = blockIdx.y*128;
    __shared__ __align__(16) float As[16][132];
    __shared__ __align__(16) float Bs[16][132];
    int tid = threadIdx.x;
    int ty = tid >> 4, tx = tid & 15;
    int lq = tid >> 5;           // 0..7
    int lc = (tid & 31) * 4;     // 0..124
    const float* Ap0 = HT + (size_t)lq*Lw + m0 + lc;
    const float* Ap1 = HT + (size_t)(lq+8)*Lw + m0 + lc;
    int o  = (n0 + lc) >> 6;
    int kb = (lc & 63) >> 1;
    const float* wr0 = wrS + (size_t)lq*8192 + (size_t)o*32 + kb;
    const float* wi0 = wiS + (size_t)lq*8192 + (size_t)o*32 + kb;
    float4 fa0 = ldg4(Ap0), fa1 = ldg4(Ap1);
    float2 r0 = ldg2(wr0),           i0 = ldg2(wi0);
    float2 r1 = ldg2(wr0 + 8*8192),  i1 = ldg2(wi0 + 8*8192);
    vf2 acc[4][8] = {};
    for (int kt = 0; kt < 256; kt += 16) {
        __syncthreads();
        *reinterpret_cast<float4*>(&As[lq][lc])   = fa0;
        *reinterpret_cast<float4*>(&As[lq+8][lc]) = fa1;
        *reinterpret_cast<float4*>(&Bs[lq][lc])   = make_float4(r0.x, i0.x, r0.y, i0.y);
        *reinterpret_cast<float4*>(&Bs[lq+8][lc]) = make_float4(r1.x, i1.x, r1.y, i1.y);
        __syncthreads();
        if (kt + 16 < 256) {
            fa0 = ldg4(Ap0 + (size_t)(kt+16)*Lw);
            fa1 = ldg4(Ap1 + (size_t)(kt+16)*Lw);
            r0 = ldg2(wr0 + (size_t)(kt+16)*8192);
            i0 = ldg2(wi0 + (size_t)(kt+16)*8192);
            r1 = ldg2(wr0 + (size_t)(kt+24)*8192);
            i1 = ldg2(wi0 + (size_t)(kt+24)*8192);
        }
        #pragma unroll
        for (int q = 0; q < 16; q++) {
            float4 a0 = *reinterpret_cast<float4*>(&As[q][ty*8]);
            float4 a1 = *reinterpret_cast<float4*>(&As[q][ty*8+4]);
            float4 b0 = *reinterpret_cast<float4*>(&Bs[q][tx*4]);
            float4 b1 = *reinterpret_cast<float4*>(&Bs[q][64+tx*4]);
            vf2 ap[4] = {{a0.x,a0.y},{a0.z,a0.w},{a1.x,a1.y},{a1.z,a1.w}};
            float bv[8] = {b0.x,b0.y,b0.z,b0.w,b1.x,b1.y,b1.z,b1.w};
            #pragma unroll
            for (int rp = 0; rp < 4; rp++) {
                #pragma unroll
                for (int j = 0; j < 8; j++) {
                    vf2 bb = {bv[j], bv[j]};
                    acc[rp][j] = fma2(ap[rp], bb, acc[rp][j]);
                }
            }
        }
    }
    #pragma unroll
    for (int rp = 0; rp < 4; rp++) {
        int r0w = m0 + ty*8 + rp*2;
        if (r0w < Lw) {
            float* p = C + (size_t)r0w*16384 + n0 + tx*4;
            *reinterpret_cast<float4*>(p)    = make_float4(acc[rp][0].x, acc[rp][1].x, acc[rp][2].x, acc[rp][3].x);
            *reinterpret_cast<float4*>(p+64) = make_float4(acc[rp][4].x, acc[rp][5].x, acc[rp][6].x, acc[rp][7].x);
        }
        if (r0w + 1 < Lw) {
            float* p = C + (size_t)(r0w+1)*16384 + n0 + tx*4;
            *reinterpret_cast<float4*>(p)    = make_float4(acc[rp][0].y, acc[rp][1].y, acc[rp][2].y, acc[rp][3].y);
            *reinterpret_cast<float4*>(p+64) = make_float4(acc[rp][4].y, acc[rp][5].y, acc[rp][6].y, acc[rp][7].y);
        }
    }
}

// pass 1 of m-scan over Call: per-chunk complex partials of sum_m w^m * Ck[m,o]
__global__ void k_cscan1(const float2* __restrict__ Call2, const float2* __restrict__ twm,
                         float2* __restrict__ psum, int s, int cgbase) {
    int cl = blockIdx.x;
    int tid = threadIdx.x;
    int k = tid & 31, ol = tid >> 5;
    int o = blockIdx.y*8 + ol;
    const float2* tws = twm + d_twoff(s);
    int mbase = cl*CH;
    float pr = 0.f, pi = 0.f;
    for (int mm = 0; mm < CH; mm++) {
        int m = mbase + mm;
        float2 cc = Call2[(size_t)m*8192 + o*32 + k];
        float2 t  = tws[(size_t)m*32 + k];
        pr = fmaf(t.x, cc.x, pr); pr = fmaf(-t.y, cc.y, pr);
        pi = fmaf(t.x, cc.y, pi); pi = fmaf(t.y, cc.x, pi);
    }
    psum[((size_t)(cgbase+cl))*8192 + o*32 + k] = make_float2(pr, pi);
}

// pass 2: rescan with chunk offset, contract over k -> Qall rows
__global__ void k_cscan2(const float2* __restrict__ Call2, const float2* __restrict__ twm,
                         const float2* __restrict__ gtm, const float2* __restrict__ psum,
                         float* __restrict__ Qrow, int s, int cgbase, int Lw) {
    int cl = blockIdx.x;
    int tid = threadIdx.x;
    int k = tid & 31, ol = tid >> 5;
    int o = blockIdx.y*8 + ol;
    const float2* tws = twm + d_twoff(s);
    const float2* gts = gtm + d_twoff(s);
    float pr = 0.f, pi = 0.f;
    for (int c = 0; c < cl; c++) {
        float2 p = psum[((size_t)(cgbase+c))*8192 + o*32 + k];
        pr += p.x; pi += p.y;
    }
    int mbase = cl*CH;
    for (int mm = 0; mm < CH; mm++) {
        int m = mbase + mm;
        float2 cc = Call2[(size_t)m*8192 + o*32 + k];
        float2 t  = tws[(size_t)m*32 + k];
        pr = fmaf(t.x, cc.x, pr); pr = fmaf(-t.y, cc.y, pr);
        pi = fmaf(t.x, cc.y, pi); pi = fmaf(t.y, cc.x, pi);
        int r = Lw - 1 - m;
        float2 g = gts[(size_t)r*32 + k];
        float qv = g.x*pr - g.y*pi;
        qv += __shfl_xor(qv, 16);
        qv += __shfl_xor(qv, 8);
        qv += __shfl_xor(qv, 4);
        qv += __shfl_xor(qv, 2);
        qv += __shfl_xor(qv, 1);
        if (k == 0) Qrow[(size_t)r*256 + o] = qv;
    }
}

// T[r,p] = sum_o Q[r,o] * Esub[p,o]   (batched over all scales)
__global__ void __launch_bounds__(256) k_tgemm(const float* __restrict__ Qall,
                                               const float* __restrict__ E0,
                                               const float* __restrict__ E1,
                                               const float* __restrict__ E2,
                                               float* __restrict__ T) {
    int mtg = blockIdx.x;
    int s, lm, Lw, rowoff, Toff;
    if (mtg < 3)      { s=0; lm=mtg;   Lw=192; rowoff=0;   Toff=0; }
    else if (mtg < 9) { s=1; lm=mtg-3; Lw=384; rowoff=192; Toff=36864; }
    else              { s=2; lm=mtg-9; Lw=768; rowoff=576; Toff=110592; }
    const float* Es = (s==0) ? E0 : ((s==1) ? E1 : E2);
    gemm64nt(Qall + (size_t)rowoff*256, 256, Lw,
             Es + (size_t)(Lw-192)*256, 256,
             T + Toff, 192, lm*64, blockIdx.y*64, 256);
}

// Mtot[p,t] = sum_i mw[i] * T_i[t-off_i, p]
__global__ void k_mtot(const float* __restrict__ T, const float* __restrict__ mlpw,
                       float* __restrict__ M) {
    int i = blockIdx.x*256 + threadIdx.x;
    if (i >= 192*768) return;
    int p = i / 768, t = i % 768;
    float v = mlpw[2] * T[110592 + (size_t)t*192 + p];
    if (t >= 384) v += mlpw[1] * T[36864 + (size_t)(t-384)*192 + p];
    if (t >= 576) v += mlpw[0] * T[(size_t)(t-576)*192 + p];
    M[i] = v;
}

// out[b,p,j]: each thread computes 4 p's for one output column cc.
// M rows staged in LDS (broadcast reads); xn reads coalesced over cc.
__global__ void __launch_bounds__(256) k_final2(
    const float* __restrict__ M, const float* __restrict__ xn,
    const float* __restrict__ aw, const float* __restrict__ ab,
    const float* __restrict__ meanb, const float* __restrict__ stdb,
    const float* __restrict__ mlpb, float* __restrict__ out)
{
    __shared__ float Ms[4*768];
    int tid = threadIdx.x;
    int pg = blockIdx.y;
    #pragma unroll
    for (int e = tid; e < 3072; e += 256)
        Ms[e] = M[(size_t)pg*3072 + e];
    __syncthreads();
    int cc = blockIdx.x*256 + tid;
    if (cc >= BE) return;
    int b = (cc >= ENC) ? 1 : 0;
    int j = cc - b*ENC;
    const float* xp = xn + (size_t)b*SEQ*ENC + j;
    float a0 = 0.f, a1 = 0.f, a2 = 0.f, a3 = 0.f;
    #pragma unroll 4
    for (int t = 0; t < 768; t++) {
        float xv = xp[(size_t)t*ENC];
        a0 = fmaf(Ms[t],        xv, a0);
        a1 = fmaf(Ms[768 + t],  xv, a1);
        a2 = fmaf(Ms[1536 + t], xv, a2);
        a3 = fmaf(Ms[2304 + t], xv, a3);
    }
    float mb = mlpb[0];
    float inv = 1.f / (aw[j] + 1e-10f);
    float sd = stdb[b*ENC + j], mn = meanb[b*ENC + j], abj = ab[j];
    float acc4[4] = {a0, a1, a2, a3};
    #pragma unroll
    for (int u = 0; u < 4; u++) {
        int p = pg*4 + u;
        float v = (acc4[u] + mb - abj) * inv * sd + mn;
        out[(size_t)b*(PRED*ENC) + (size_t)p*ENC + j] = v;
    }
}

// ------------------------------------------------------------------
extern "C" void kernel_launch(void* const* d_in, const int* in_sizes, int n_in,
                              void* d_out, int out_size, void* d_ws, size_t ws_size,
                              hipStream_t stream)
{
    const float* hist = (const float*)d_in[0];
    const float* aw   = (const float*)d_in[2];
    const float* ab   = (const float*)d_in[3];
    const float* Ast  = (const float*)d_in[4];
    const float* Bst  = (const float*)d_in[5];
    const float* E0   = (const float*)d_in[6];
    const float* E1   = (const float*)d_in[7];
    const float* E2   = (const float*)d_in[8];
    const float* wr   = (const float*)d_in[9];
    const float* wi   = (const float*)d_in[10];
    const float* mlpw = (const float*)d_in[11];
    const float* mlpb = (const float*)d_in[12];
    float* out = (float*)d_out;

    float* w = (float*)d_ws;
    float* xn    = w; w += 493056;
    float* meanb = w; w += 642;
    float* stdb  = w; w += 642;
    float* Hbuf  = w; w += 344064;
    float* HT    = w; w += 344064;
    float* apow  = w; w += 393216;
    float2* twm  = (float2*)w; w += 86016;
    float2* gtm  = (float2*)w; w += 86016;
    float2* psum = (float2*)w; w += 458752;   // 28 chunk-groups x 8192 float2
    float* Call  = w; w += 12582912;          // up to 768 x 16384 (per scale, reused)
    float* Qall  = w; w += 344064;            // 1344 x 256
    float* Tbuf  = w; w += 258048;
    float* Mt    = w; w += 147456;
    // total ~15.5M floats = 62 MB (< 78 MB proven)

    k_stats<<<dim3(6,2), dim3(64,4), 0, stream>>>(hist, meanb, stdb);
    k_norm<<<1926, 256, 0, stream>>>(hist, meanb, stdb, aw, ab, xn);
    k_tw<<<168, 256, 0, stream>>>(twm, gtm);
    k_hinit<<<768, 256, 0, stream>>>(Ast, Bst, apow, Hbuf);
    for (int lev = 0; lev < 10; lev++)
        k_hlevel<<<dim3(4,8,3), 256, 0, stream>>>(Hbuf, apow, lev & 1, 1 << lev);
    k_htr<<<1344, 256, 0, stream>>>(Hbuf, HT);

    const int Lws[3]    = {192, 384, 768};
    const int cgbase[3] = {0, 4, 12};
    const int rowoff[3] = {0, 192, 576};
    for (int s = 0; s < 3; s++) {
        int Lw = Lws[s];
        int nch = Lw / CH;
        int mt  = (Lw + 127) / 128;
        k_cgemm<<<dim3(mt, 128), 256, 0, stream>>>(HT + d_Hoff(s),
                                                   wr + (size_t)s*2097152,
                                                   wi + (size_t)s*2097152, Call, Lw);
        k_cscan1<<<dim3(nch, 32), 256, 0, stream>>>((const float2*)Call, twm, psum, s, cgbase[s]);
        k_cscan2<<<dim3(nch, 32), 256, 0, stream>>>((const float2*)Call, twm, gtm, psum,
                                                    Qall + (size_t)rowoff[s]*256, s, cgbase[s], Lw);
    }
    k_tgemm<<<dim3(21,3), 256, 0, stream>>>(Qall, E0, E1, E2, Tbuf);
    k_mtot<<<576, 256, 0, stream>>>(Tbuf, mlpw, Mt);
    k_final2<<<dim3(3, 48), 256, 0, stream>>>(Mt, xn, aw, ab, meanb, stdb, mlpb, out);
}

// Round 7
// 507.496 us; speedup vs baseline: 1.2712x; 1.0501x over previous
//
#include <hip/hip_runtime.h>

#define SEQ 768
#define PRED 192
#define ENC 321
#define NB 2
#define BE (NB*ENC)
#define CH 48

typedef float vf2 __attribute__((ext_vector_type(2)));

union F4V2 { float4 f4; vf2 v2[2]; };

__device__ __forceinline__ float4 ldg4(const float* p) {
    return *reinterpret_cast<const float4*>(p);
}
__device__ __forceinline__ float2 ldg2(const float* p) {
    return *reinterpret_cast<const float2*>(p);
}
// packed fp32 FMA, a.lo broadcast to both lanes (even row):
// D.lo = a.lo*b.lo + D.lo ; D.hi = a.lo*b.hi + D.hi
__device__ __forceinline__ void pklo(vf2& c, vf2 a, vf2 b) {
    asm("v_pk_fma_f32 %0, %1, %2, %0 op_sel:[0,0,0] op_sel_hi:[0,1,1]"
        : "+v"(c) : "v"(a), "v"(b));
}
// a.hi broadcast (odd row): D.lo = a.hi*b.lo + D.lo ; D.hi = a.hi*b.hi + D.hi
__device__ __forceinline__ void pkhi(vf2& c, vf2 a, vf2 b) {
    asm("v_pk_fma_f32 %0, %1, %2, %0 op_sel:[1,0,0] op_sel_hi:[1,1,1]"
        : "+v"(c) : "v"(a), "v"(b));
}

__host__ __device__ __forceinline__ int d_Lw(int s)    { return s==0?192:(s==1?384:768); }
__host__ __device__ __forceinline__ int d_Hoff(int s)  { return s==0?0:(s==1?49152:147456); }
__host__ __device__ __forceinline__ int d_twoff(int s) { return s==0?0:(s==1?6144:18432); }

// ------------------------------------------------------------------
__global__ void k_stats(const float* __restrict__ hist,
                        float* __restrict__ meanb, float* __restrict__ stdb) {
    int j  = blockIdx.x*64 + threadIdx.x;
    int b  = blockIdx.y;
    int ty = threadIdx.y;
    float s = 0.f, s2 = 0.f;
    if (j < ENC) {
        for (int t = ty; t < SEQ; t += 4) {
            float v = hist[(size_t)b*SEQ*ENC + (size_t)t*ENC + j];
            s += v; s2 += v*v;
        }
    }
    __shared__ float l1[4][64], l2[4][64];
    l1[ty][threadIdx.x] = s; l2[ty][threadIdx.x] = s2;
    __syncthreads();
    if (ty == 0 && j < ENC) {
        float S  = l1[0][threadIdx.x]+l1[1][threadIdx.x]+l1[2][threadIdx.x]+l1[3][threadIdx.x];
        float S2 = l2[0][threadIdx.x]+l2[1][threadIdx.x]+l2[2][threadIdx.x]+l2[3][threadIdx.x];
        float m   = S * (1.f/SEQ);
        float var = S2 * (1.f/SEQ) - m*m;
        meanb[b*ENC+j] = m;
        stdb[b*ENC+j]  = sqrtf(var + 1e-5f);
    }
}

__global__ void k_norm(const float* __restrict__ hist,
                       const float* __restrict__ meanb, const float* __restrict__ stdb,
                       const float* __restrict__ aw, const float* __restrict__ ab,
                       float* __restrict__ xn) {
    int i = blockIdx.x*256 + threadIdx.x;
    if (i >= NB*SEQ*ENC) return;
    int j = i % ENC;
    int b = i / (SEQ*ENC);
    float v = (hist[i] - meanb[b*ENC+j]) / stdb[b*ENC+j];
    xn[i] = v * aw[j] + ab[j];
}

// twm[s][m][k] = e^{-2pi i k m / Lw};  gtm[s][r][k] = kappa_k e^{+2pi i k (191-r)/Lw}
__global__ void k_tw(float2* __restrict__ twm, float2* __restrict__ gtm) {
    int i = blockIdx.x*256 + threadIdx.x;
    if (i >= 43008) return;
    int s, rem;
    if (i < 6144)       { s=0; rem=i; }
    else if (i < 18432) { s=1; rem=i-6144; }
    else                { s=2; rem=i-18432; }
    int Lw = d_Lw(s);
    int k = rem & 31, m = rem >> 5;
    const float TWO_PI = 6.28318530717958647692f;
    int km = (k*m) % Lw;
    float c, sn;
    sincosf(TWO_PI * km / Lw, &sn, &c);
    twm[i] = make_float2(c, -sn);
    int e = (k*(PRED-1-m)) % Lw; if (e < 0) e += Lw;
    float c2, s2v;
    sincosf(TWO_PI * e / Lw, &s2v, &c2);
    float coef = (k==0 ? 1.f : 2.f) / (float)Lw;
    gtm[i] = make_float2(coef*c2, coef*s2v);
}

__global__ void k_hinit(const float* __restrict__ Ast, const float* __restrict__ Bst,
                        float* __restrict__ apow, float* __restrict__ Hbuf) {
    int i = blockIdx.x*256 + threadIdx.x;
    if (i < 3*65536) apow[i] = Ast[i];
    if (i < 3*256) {
        int s = i >> 8, n = i & 255;
        Hbuf[d_Hoff(s) + n] = Bst[i];
    }
}

// ---------- 64x64 tile GEMM cores (pk-fma asm + register prefetch) ----------
// NT: C[m,n] = sum_q A[m,q]*B[n,q]
__device__ __forceinline__ void gemm64nt(
    const float* __restrict__ A, int lda, int Arows,
    const float* __restrict__ B, int ldb,
    float* __restrict__ C, int ldc, int m0, int n0, int K)
{
    __shared__ __align__(16) float AsT[16][68];
    __shared__ __align__(16) float BsT[16][68];
    int tid = threadIdx.x;
    int tm = tid >> 4, tn = tid & 15;
    int lr = tid >> 2, lq = (tid & 3)*4;
    bool aok = (m0 + lr) < Arows;
    const float* Ap = A + (size_t)(m0+lr)*lda + lq;
    const float* Bp = B + (size_t)(n0+lr)*ldb + lq;
    float4 fa = aok ? ldg4(Ap) : make_float4(0.f,0.f,0.f,0.f);
    float4 fb = ldg4(Bp);
    vf2 acc[4][2] = {};
    for (int kt = 0; kt < K; kt += 16) {
        __syncthreads();
        AsT[lq+0][lr]=fa.x; AsT[lq+1][lr]=fa.y; AsT[lq+2][lr]=fa.z; AsT[lq+3][lr]=fa.w;
        BsT[lq+0][lr]=fb.x; BsT[lq+1][lr]=fb.y; BsT[lq+2][lr]=fb.z; BsT[lq+3][lr]=fb.w;
        __syncthreads();
        if (kt + 16 < K) {
            fa = aok ? ldg4(Ap + kt + 16) : make_float4(0.f,0.f,0.f,0.f);
            fb = ldg4(Bp + kt + 16);
        }
        #pragma unroll
        for (int q = 0; q < 16; q++) {
            F4V2 ua, ub;
            ua.f4 = *reinterpret_cast<float4*>(&AsT[q][tm*4]);
            ub.f4 = *reinterpret_cast<float4*>(&BsT[q][tn*4]);
            #pragma unroll
            for (int ra = 0; ra < 2; ra++)
                #pragma unroll
                for (int cp = 0; cp < 2; cp++) {
                    pklo(acc[2*ra+0][cp], ua.v2[ra], ub.v2[cp]);
                    pkhi(acc[2*ra+1][cp], ua.v2[ra], ub.v2[cp]);
                }
        }
    }
    #pragma unroll
    for (int r = 0; r < 4; r++) {
        int m = m0 + tm*4 + r; if (m >= Arows) continue;
        float4 o4 = make_float4(acc[r][0].x, acc[r][0].y, acc[r][1].x, acc[r][1].y);
        *reinterpret_cast<float4*>(C + (size_t)m*ldc + n0 + tn*4) = o4;
    }
}

// NN: C[m,n] = sum_q A[m,q]*B[q,n]
__device__ __forceinline__ void gemm64nn(
    const float* __restrict__ A, int lda,
    const float* __restrict__ B, int ldb,
    float* __restrict__ C, int ldc, int m0, int n0, int K)
{
    __shared__ __align__(16) float AsT[16][68];
    __shared__ __align__(16) float Bs[16][68];
    int tid = threadIdx.x;
    int tm = tid >> 4, tn = tid & 15;
    int lr = tid >> 2, lq = (tid & 3)*4;
    int blq = tid >> 4, blc = (tid & 15)*4;
    const float* Ap = A + (size_t)(m0+lr)*lda + lq;
    const float* Bp = B + (size_t)blq*ldb + n0 + blc;
    float4 fa = ldg4(Ap);
    float4 fb = ldg4(Bp);
    vf2 acc[4][2] = {};
    for (int kt = 0; kt < K; kt += 16) {
        __syncthreads();
        AsT[lq+0][lr]=fa.x; AsT[lq+1][lr]=fa.y; AsT[lq+2][lr]=fa.z; AsT[lq+3][lr]=fa.w;
        *reinterpret_cast<float4*>(&Bs[blq][blc]) = fb;
        __syncthreads();
        if (kt + 16 < K) {
            fa = ldg4(Ap + kt + 16);
            fb = ldg4(Bp + (size_t)(kt+16)*ldb);
        }
        #pragma unroll
        for (int q = 0; q < 16; q++) {
            F4V2 ua, ub;
            ua.f4 = *reinterpret_cast<float4*>(&AsT[q][tm*4]);
            ub.f4 = *reinterpret_cast<float4*>(&Bs[q][tn*4]);
            #pragma unroll
            for (int ra = 0; ra < 2; ra++)
                #pragma unroll
                for (int cp = 0; cp < 2; cp++) {
                    pklo(acc[2*ra+0][cp], ua.v2[ra], ub.v2[cp]);
                    pkhi(acc[2*ra+1][cp], ua.v2[ra], ub.v2[cp]);
                }
        }
    }
    #pragma unroll
    for (int r = 0; r < 4; r++) {
        int m = m0 + tm*4 + r;
        float4 o4 = make_float4(acc[r][0].x, acc[r][0].y, acc[r][1].x, acc[r][1].y);
        *reinterpret_cast<float4*>(C + (size_t)m*ldc + n0 + tn*4) = o4;
    }
}

// one doubling level: fill H[mc..min(2mc,Lw)) = H[0..]*Apow^T ; square Apow
__global__ void __launch_bounds__(256) k_hlevel(float* __restrict__ Hbuf,
                                                float* __restrict__ apow,
                                                int par, int mc) {
    int s = blockIdx.z;
    int Lw = d_Lw(s);
    const float* Asrc = apow + (size_t)par*196608 + (size_t)s*65536;
    float* Adst       = apow + (size_t)(1-par)*196608 + (size_t)s*65536;
    float* H = Hbuf + d_Hoff(s);
    int yt = blockIdx.y, xt = blockIdx.x;
    if (yt < 4) {
        if (mc >= Lw) return;
        int rows = min(mc, Lw - mc);
        if (yt*64 >= rows) return;
        gemm64nt(H, 256, rows, Asrc, 256, H + (size_t)mc*256, 256,
                 yt*64, xt*64, 256);
    } else {
        if (2*mc >= Lw) return;
        gemm64nn(Asrc, 256, Asrc, 256, Adst, 256, (yt-4)*64, xt*64, 256);
    }
}

// transpose H (Lw x 256) -> HT (256 x Lw), per scale
__global__ void k_htr(const float* __restrict__ Hbuf, float* __restrict__ HT) {
    int i = blockIdx.x*256 + threadIdx.x;
    if (i >= 344064) return;
    int s, rem;
    if (i < 49152)       { s=0; rem=i; }
    else if (i < 147456) { s=1; rem=i-49152; }
    else                 { s=2; rem=i-147456; }
    int Lw = d_Lw(s);
    int k = rem / Lw, m = rem - k*Lw;
    HT[i] = Hbuf[d_Hoff(s) + (size_t)m*256 + k];
}

// Call (Lw x 16384) = HT^T (Lw x 256) * Bpack (256 x 16384)
// Bpack not materialized: col = o*64 + k*2 + c -> (c?wi:wr)[n,o,k].
// 128x128 tiles, 8x8 per-thread acc via v_pk_fma_f32 op_sel (no dup movs).
__global__ void __launch_bounds__(256) k_cgemm(
    const float* __restrict__ HT, const float* __restrict__ wrS,
    const float* __restrict__ wiS, float* __restrict__ C, int Lw)
{
    int m0 = blockIdx.x*128, n0 = blockIdx.y*128;
    __shared__ __align__(16) float As[16][132];
    __shared__ __align__(16) float Bs[16][132];
    int tid = threadIdx.x;
    int ty = tid >> 4, tx = tid & 15;
    int lq = tid >> 5;           // 0..7
    int lc = (tid & 31) * 4;     // 0..124
    const float* Ap0 = HT + (size_t)lq*Lw + m0 + lc;
    const float* Ap1 = HT + (size_t)(lq+8)*Lw + m0 + lc;
    int o  = (n0 + lc) >> 6;
    int kb = (lc & 63) >> 1;
    const float* wr0 = wrS + (size_t)lq*8192 + (size_t)o*32 + kb;
    const float* wi0 = wiS + (size_t)lq*8192 + (size_t)o*32 + kb;
    float4 fa0 = ldg4(Ap0), fa1 = ldg4(Ap1);
    float2 r0 = ldg2(wr0),           i0 = ldg2(wi0);
    float2 r1 = ldg2(wr0 + 8*8192),  i1 = ldg2(wi0 + 8*8192);
    vf2 acc[8][4] = {};
    for (int kt = 0; kt < 256; kt += 16) {
        __syncthreads();
        *reinterpret_cast<float4*>(&As[lq][lc])   = fa0;
        *reinterpret_cast<float4*>(&As[lq+8][lc]) = fa1;
        *reinterpret_cast<float4*>(&Bs[lq][lc])   = make_float4(r0.x, i0.x, r0.y, i0.y);
        *reinterpret_cast<float4*>(&Bs[lq+8][lc]) = make_float4(r1.x, i1.x, r1.y, i1.y);
        __syncthreads();
        if (kt + 16 < 256) {
            fa0 = ldg4(Ap0 + (size_t)(kt+16)*Lw);
            fa1 = ldg4(Ap1 + (size_t)(kt+16)*Lw);
            r0 = ldg2(wr0 + (size_t)(kt+16)*8192);
            i0 = ldg2(wi0 + (size_t)(kt+16)*8192);
            r1 = ldg2(wr0 + (size_t)(kt+24)*8192);
            i1 = ldg2(wi0 + (size_t)(kt+24)*8192);
        }
        #pragma unroll
        for (int q = 0; q < 16; q++) {
            F4V2 ua0, ua1, ub0, ub1;
            ua0.f4 = *reinterpret_cast<float4*>(&As[q][ty*8]);
            ua1.f4 = *reinterpret_cast<float4*>(&As[q][ty*8+4]);
            ub0.f4 = *reinterpret_cast<float4*>(&Bs[q][tx*4]);
            ub1.f4 = *reinterpret_cast<float4*>(&Bs[q][64+tx*4]);
            vf2 apair[4] = {ua0.v2[0], ua0.v2[1], ua1.v2[0], ua1.v2[1]};
            vf2 bpair[4] = {ub0.v2[0], ub0.v2[1], ub1.v2[0], ub1.v2[1]};
            #pragma unroll
            for (int ra = 0; ra < 4; ra++)
                #pragma unroll
                for (int cp = 0; cp < 4; cp++) {
                    pklo(acc[2*ra+0][cp], apair[ra], bpair[cp]);
                    pkhi(acc[2*ra+1][cp], apair[ra], bpair[cp]);
                }
        }
    }
    #pragma unroll
    for (int r = 0; r < 8; r++) {
        int row = m0 + ty*8 + r;
        if (row < Lw) {
            float* p = C + (size_t)row*16384 + n0 + tx*4;
            *reinterpret_cast<float4*>(p)    = make_float4(acc[r][0].x, acc[r][0].y, acc[r][1].x, acc[r][1].y);
            *reinterpret_cast<float4*>(p+64) = make_float4(acc[r][2].x, acc[r][2].y, acc[r][3].x, acc[r][3].y);
        }
    }
}

// pass 1 of m-scan over Call: per-chunk complex partials of sum_m w^m * Ck[m,o]
__global__ void k_cscan1(const float2* __restrict__ Call2, const float2* __restrict__ twm,
                         float2* __restrict__ psum, int s, int cgbase) {
    int cl = blockIdx.x;
    int tid = threadIdx.x;
    int k = tid & 31, ol = tid >> 5;
    int o = blockIdx.y*8 + ol;
    const float2* tws = twm + d_twoff(s);
    int mbase = cl*CH;
    float pr = 0.f, pi = 0.f;
    for (int mm = 0; mm < CH; mm++) {
        int m = mbase + mm;
        float2 cc = Call2[(size_t)m*8192 + o*32 + k];
        float2 t  = tws[(size_t)m*32 + k];
        pr = fmaf(t.x, cc.x, pr); pr = fmaf(-t.y, cc.y, pr);
        pi = fmaf(t.x, cc.y, pi); pi = fmaf(t.y, cc.x, pi);
    }
    psum[((size_t)(cgbase+cl))*8192 + o*32 + k] = make_float2(pr, pi);
}

// pass 2: rescan with chunk offset, contract over k -> Qall rows
__global__ void k_cscan2(const float2* __restrict__ Call2, const float2* __restrict__ twm,
                         const float2* __restrict__ gtm, const float2* __restrict__ psum,
                         float* __restrict__ Qrow, int s, int cgbase, int Lw) {
    int cl = blockIdx.x;
    int tid = threadIdx.x;
    int k = tid & 31, ol = tid >> 5;
    int o = blockIdx.y*8 + ol;
    const float2* tws = twm + d_twoff(s);
    const float2* gts = gtm + d_twoff(s);
    float pr = 0.f, pi = 0.f;
    for (int c = 0; c < cl; c++) {
        float2 p = psum[((size_t)(cgbase+c))*8192 + o*32 + k];
        pr += p.x; pi += p.y;
    }
    int mbase = cl*CH;
    for (int mm = 0; mm < CH; mm++) {
        int m = mbase + mm;
        float2 cc = Call2[(size_t)m*8192 + o*32 + k];
        float2 t  = tws[(size_t)m*32 + k];
        pr = fmaf(t.x, cc.x, pr); pr = fmaf(-t.y, cc.y, pr);
        pi = fmaf(t.x, cc.y, pi); pi = fmaf(t.y, cc.x, pi);
        int r = Lw - 1 - m;
        float2 g = gts[(size_t)r*32 + k];
        float qv = g.x*pr - g.y*pi;
        qv += __shfl_xor(qv, 16);
        qv += __shfl_xor(qv, 8);
        qv += __shfl_xor(qv, 4);
        qv += __shfl_xor(qv, 2);
        qv += __shfl_xor(qv, 1);
        if (k == 0) Qrow[(size_t)r*256 + o] = qv;
    }
}

// T[r,p] = sum_o Q[r,o] * Esub[p,o]   (batched over all scales)
__global__ void __launch_bounds__(256) k_tgemm(const float* __restrict__ Qall,
                                               const float* __restrict__ E0,
                                               const float* __restrict__ E1,
                                               const float* __restrict__ E2,
                                               float* __restrict__ T) {
    int mtg = blockIdx.x;
    int s, lm, Lw, rowoff, Toff;
    if (mtg < 3)      { s=0; lm=mtg;   Lw=192; rowoff=0;   Toff=0; }
    else if (mtg < 9) { s=1; lm=mtg-3; Lw=384; rowoff=192; Toff=36864; }
    else              { s=2; lm=mtg-9; Lw=768; rowoff=576; Toff=110592; }
    const float* Es = (s==0) ? E0 : ((s==1) ? E1 : E2);
    gemm64nt(Qall + (size_t)rowoff*256, 256, Lw,
             Es + (size_t)(Lw-192)*256, 256,
             T + Toff, 192, lm*64, blockIdx.y*64, 256);
}

// Mtot[p,t] = sum_i mw[i] * T_i[t-off_i, p]
__global__ void k_mtot(const float* __restrict__ T, const float* __restrict__ mlpw,
                       float* __restrict__ M) {
    int i = blockIdx.x*256 + threadIdx.x;
    if (i >= 192*768) return;
    int p = i / 768, t = i % 768;
    float v = mlpw[2] * T[110592 + (size_t)t*192 + p];
    if (t >= 384) v += mlpw[1] * T[36864 + (size_t)(t-384)*192 + p];
    if (t >= 576) v += mlpw[0] * T[(size_t)(t-576)*192 + p];
    M[i] = v;
}

// out[b,p,j]: each thread computes 4 p's for one output column cc.
__global__ void __launch_bounds__(256) k_final2(
    const float* __restrict__ M, const float* __restrict__ xn,
    const float* __restrict__ aw, const float* __restrict__ ab,
    const float* __restrict__ meanb, const float* __restrict__ stdb,
    const float* __restrict__ mlpb, float* __restrict__ out)
{
    __shared__ float Ms[4*768];
    int tid = threadIdx.x;
    int pg = blockIdx.y;
    #pragma unroll
    for (int e = tid; e < 3072; e += 256)
        Ms[e] = M[(size_t)pg*3072 + e];
    __syncthreads();
    int cc = blockIdx.x*256 + tid;
    if (cc >= BE) return;
    int b = (cc >= ENC) ? 1 : 0;
    int j = cc - b*ENC;
    const float* xp = xn + (size_t)b*SEQ*ENC + j;
    float a0 = 0.f, a1 = 0.f, a2 = 0.f, a3 = 0.f;
    #pragma unroll 4
    for (int t = 0; t < 768; t++) {
        float xv = xp[(size_t)t*ENC];
        a0 = fmaf(Ms[t],        xv, a0);
        a1 = fmaf(Ms[768 + t],  xv, a1);
        a2 = fmaf(Ms[1536 + t], xv, a2);
        a3 = fmaf(Ms[2304 + t], xv, a3);
    }
    float mb = mlpb[0];
    float inv = 1.f / (aw[j] + 1e-10f);
    float sd = stdb[b*ENC + j], mn = meanb[b*ENC + j], abj = ab[j];
    float acc4[4] = {a0, a1, a2, a3};
    #pragma unroll
    for (int u = 0; u < 4; u++) {
        int p = pg*4 + u;
        float v = (acc4[u] + mb - abj) * inv * sd + mn;
        out[(size_t)b*(PRED*ENC) + (size_t)p*ENC + j] = v;
    }
}

// ------------------------------------------------------------------
extern "C" void kernel_launch(void* const* d_in, const int* in_sizes, int n_in,
                              void* d_out, int out_size, void* d_ws, size_t ws_size,
                              hipStream_t stream)
{
    const float* hist = (const float*)d_in[0];
    const float* aw   = (const float*)d_in[2];
    const float* ab   = (const float*)d_in[3];
    const float* Ast  = (const float*)d_in[4];
    const float* Bst  = (const float*)d_in[5];
    const float* E0   = (const float*)d_in[6];
    const float* E1   = (const float*)d_in[7];
    const float* E2   = (const float*)d_in[8];
    const float* wr   = (const float*)d_in[9];
    const float* wi   = (const float*)d_in[10];
    const float* mlpw = (const float*)d_in[11];
    const float* mlpb = (const float*)d_in[12];
    float* out = (float*)d_out;

    float* w = (float*)d_ws;
    float* xn    = w; w += 493056;
    float* meanb = w; w += 642;
    float* stdb  = w; w += 642;
    float* Hbuf  = w; w += 344064;
    float* HT    = w; w += 344064;
    float* apow  = w; w += 393216;
    float2* twm  = (float2*)w; w += 86016;
    float2* gtm  = (float2*)w; w += 86016;
    float2* psum = (float2*)w; w += 458752;   // 28 chunk-groups x 8192 float2
    float* Call  = w; w += 12582912;          // up to 768 x 16384 (per scale, reused)
    float* Qall  = w; w += 344064;            // 1344 x 256
    float* Tbuf  = w; w += 258048;
    float* Mt    = w; w += 147456;
    // total ~15.5M floats = 62 MB (< 78 MB proven)

    k_stats<<<dim3(6,2), dim3(64,4), 0, stream>>>(hist, meanb, stdb);
    k_norm<<<1926, 256, 0, stream>>>(hist, meanb, stdb, aw, ab, xn);
    k_tw<<<168, 256, 0, stream>>>(twm, gtm);
    k_hinit<<<768, 256, 0, stream>>>(Ast, Bst, apow, Hbuf);
    for (int lev = 0; lev < 10; lev++)
        k_hlevel<<<dim3(4,8,3), 256, 0, stream>>>(Hbuf, apow, lev & 1, 1 << lev);
    k_htr<<<1344, 256, 0, stream>>>(Hbuf, HT);

    const int Lws[3]    = {192, 384, 768};
    const int cgbase[3] = {0, 4, 12};
    const int rowoff[3] = {0, 192, 576};
    for (int s = 0; s < 3; s++) {
        int Lw = Lws[s];
        int nch = Lw / CH;
        int mt  = (Lw + 127) / 128;
        k_cgemm<<<dim3(mt, 128), 256, 0, stream>>>(HT + d_Hoff(s),
                                                   wr + (size_t)s*2097152,
                                                   wi + (size_t)s*2097152, Call, Lw);
        k_cscan1<<<dim3(nch, 32), 256, 0, stream>>>((const float2*)Call, twm, psum, s, cgbase[s]);
        k_cscan2<<<dim3(nch, 32), 256, 0, stream>>>((const float2*)Call, twm, gtm, psum,
                                                    Qall + (size_t)rowoff[s]*256, s, cgbase[s], Lw);
    }
    k_tgemm<<<dim3(21,3), 256, 0, stream>>>(Qall, E0, E1, E2, Tbuf);
    k_mtot<<<576, 256, 0, stream>>>(Tbuf, mlpw, Mt);
    k_final2<<<dim3(3, 48), 256, 0, stream>>>(Mt, xn, aw, ab, meanb, stdb, mlpb, out);
}